// Round 8
// baseline (3371.423 us; speedup 1.0000x reference)
//
#include <hip/hip_runtime.h>

#define TPB 256
#define MAXJ 48

// role bases
#define SC_N 128
#define YD0 128
#define YU0 144
#define WD0 151
#define WU0 159
#define DT0 166
#define XP0 182
#define XR0 214
#define U0 230
#define NWG 238
#define NGRP 8
#define GCH 30  // ceil(NWG/NGRP)

// ---------------------------------------------------------------------------
// Coherent (agent-scope, MALL-served) helpers: sc1 loads/stores, no fences.
// ---------------------------------------------------------------------------
__device__ __forceinline__ void cst(float* p, float v) {
  __hip_atomic_store(p, v, __ATOMIC_RELAXED, __HIP_MEMORY_SCOPE_AGENT);
}
__device__ __forceinline__ void cstu(unsigned* p, unsigned v) {
  __hip_atomic_store(p, v, __ATOMIC_RELAXED, __HIP_MEMORY_SCOPE_AGENT);
}
__device__ __forceinline__ unsigned cldu(const unsigned* p) {
  return __hip_atomic_load(p, __ATOMIC_RELAXED, __HIP_MEMORY_SCOPE_AGENT);
}
__device__ __forceinline__ float cld(const float* p) {
  return __hip_atomic_load(p, __ATOMIC_RELAXED, __HIP_MEMORY_SCOPE_AGENT);
}
__device__ __forceinline__ float2 cld2(const float* p) {
  unsigned long long u = __hip_atomic_load(
      reinterpret_cast<const unsigned long long*>(p), __ATOMIC_RELAXED,
      __HIP_MEMORY_SCOPE_AGENT);
  float2 v;
  __builtin_memcpy(&v, &u, 8);
  return v;
}

// ---------------------------------------------------------------------------
// Hierarchical grid barrier: arrival flag per WG (padded line); 8 checker WGs
// poll ~30 local flags each and publish a group flag; everyone polls 8 group
// flags. No RMW, no cache maintenance; vmcnt drain orders data before flag.
// ---------------------------------------------------------------------------
__device__ __forceinline__ void grid_barrier(unsigned* __restrict__ arr,
                                             unsigned* __restrict__ grp,
                                             int bid, int tid, unsigned phase) {
  asm volatile("s_waitcnt vmcnt(0)" ::: "memory");
  __syncthreads();
  if (tid == 0) cstu(arr + (bid << 5), phase);
  if (bid < NGRP) {
    const int lo = bid * GCH;
    const int n = (NWG - lo < GCH) ? (NWG - lo) : GCH;
    if (tid < n) {
      while (cldu(arr + ((lo + tid) << 5)) < phase) __builtin_amdgcn_s_sleep(1);
    }
    __syncthreads();
    if (tid == 0) cstu(grp + (bid << 5), phase);
  }
  if (tid < NGRP) {
    while (cldu(grp + (tid << 5)) < phase) __builtin_amdgcn_s_sleep(1);
  }
  __atomic_signal_fence(__ATOMIC_SEQ_CST);
  __syncthreads();
}

// ---------------------------------------------------------------------------
// Tiled fp32 GEMM tile body: Z[M x N] = X[M x K] @ Y[K x N], row-major.
// ---------------------------------------------------------------------------
__device__ void gemm_tile(const float* __restrict__ X, const float* __restrict__ Y,
                          float* __restrict__ Z, int M, int N, int Kd,
                          int mtile, int ntile) {
  __shared__ float Xs[16][65];
  __shared__ float Ys[16][65];
  const int tx = threadIdx.x & 15;
  const int ty = threadIdx.x >> 4;
  const int mbase = mtile * 64;
  const int nbase = ntile * 64;
  float acc[4][4] = {};
  for (int k0 = 0; k0 < Kd; k0 += 16) {
#pragma unroll
    for (int r = 0; r < 4; ++r) {
      int idx = threadIdx.x + 256 * r;
      int mm = idx >> 4, kk = idx & 15;
      int gm = mbase + mm, gk = k0 + kk;
      Xs[kk][mm] = (gm < M && gk < Kd) ? X[(size_t)gm * Kd + gk] : 0.f;
      int nn = idx & 63, k2 = idx >> 6;
      int gn = nbase + nn, gk2 = k0 + k2;
      Ys[k2][nn] = (gk2 < Kd && gn < N) ? Y[(size_t)gk2 * N + gn] : 0.f;
    }
    __syncthreads();
#pragma unroll
    for (int kk = 0; kk < 16; ++kk) {
      float xv[4], yv[4];
#pragma unroll
      for (int a = 0; a < 4; ++a) xv[a] = Xs[kk][ty * 4 + a];
#pragma unroll
      for (int b = 0; b < 4; ++b) yv[b] = Ys[kk][tx * 4 + b];
#pragma unroll
      for (int a = 0; a < 4; ++a)
#pragma unroll
        for (int b = 0; b < 4; ++b) acc[a][b] += xv[a] * yv[b];
    }
    __syncthreads();
  }
#pragma unroll
  for (int a = 0; a < 4; ++a) {
    int gm = mbase + ty * 4 + a;
    if (gm < M) {
#pragma unroll
      for (int b = 0; b < 4; ++b) {
        int gn = nbase + tx * 4 + b;
        if (gn < N) Z[(size_t)gm * N + gn] = acc[a][b];
      }
    }
  }
}

// ---------------------------------------------------------------------------
// Batched multi-GEMM. xsel/ysel: 0=ws, 1=A, 2=B, 3=C, 4=Km.
// ---------------------------------------------------------------------------
struct JobBatch {
  int n;
  int start[MAXJ + 1];
  int xsel[MAXJ], xoff[MAXJ], ysel[MAXJ], yoff[MAXJ], zoff[MAXJ];
  int M[MAXJ], N[MAXJ], K[MAXJ];
};

__global__ __launch_bounds__(256) void multi_gemm(JobBatch jb,
    const float* __restrict__ A, const float* __restrict__ Bm,
    const float* __restrict__ C, const float* __restrict__ Km,
    float* __restrict__ ws) {
  int b = blockIdx.x;
  int j = 0;
  while (j < jb.n - 1 && b >= jb.start[j + 1]) ++j;
  int rel = b - jb.start[j];
  const float* bases[5] = {ws, A, Bm, C, Km};
  const float* X = bases[jb.xsel[j]] + jb.xoff[j];
  const float* Y = bases[jb.ysel[j]] + jb.yoff[j];
  float* Z = ws + jb.zoff[j];
  int tn = jb.N[j] >> 6;
  gemm_tile(X, Y, Z, jb.M[j], jb.N[j], jb.K[j], rel / tn, rel % tn);
}

// ---------------------------------------------------------------------------
__global__ __launch_bounds__(256) void m2_kernel(const float* __restrict__ MT,
    const float* __restrict__ sm, float* __restrict__ M2g) {
  int idx = blockIdx.x * 256 + threadIdx.x;
  if (idx >= 128 * 32 * 256) return;
  int q = idx & 255;
  int ci = idx >> 8;
  const float* base = MT + (size_t)ci * 32 * 256 + q;
  float acc = 0.f;
#pragma unroll
  for (int j = 0; j < 32; ++j) acc += base[j * 256] * sm[j];
  M2g[idx] = acc;
}

__global__ __launch_bounds__(256) void wfir_kernel(const float* __restrict__ M2g,
    const float* __restrict__ Phi, float* __restrict__ W) {
  int idx = blockIdx.x * 256 + threadIdx.x;  // j*32768 + c*256 + q
  if (idx >= 64 * 32768) return;
  int j = idx >> 15;
  int cq = idx & 32767;
  int c = cq >> 8;
  int q = cq & 255;
  float acc = 0.f;
#pragma unroll
  for (int i = 0; i < 32; ++i)
    acc = fmaf(Phi[(i << 6) | j], M2g[(size_t)(((c << 5) | i) << 8) | q], acc);
  W[idx] = acc;
}

__global__ __launch_bounds__(256) void axpy_acl(const float* __restrict__ A,
    const float* __restrict__ BKC, float* __restrict__ Acl, float* __restrict__ P1) {
  int i = blockIdx.x * 256 + threadIdx.x;
  if (i < 262144) {
    float v = A[i] - BKC[i];
    Acl[i] = v;
    P1[i] = v;
  }
}

// ---------------------------------------------------------------------------
__global__ void init_kernel(const float* __restrict__ x0, float* __restrict__ xh,
    float* __restrict__ eh, float* __restrict__ ynh, float* __restrict__ uh0,
    float* __restrict__ dbnd, unsigned* __restrict__ arr,
    unsigned* __restrict__ grp) {
  int i = blockIdx.x * 256 + threadIdx.x;
  int stride = gridDim.x * 256;
  for (int k = i; k < 524288; k += stride) cst(xh + k, 0.f);
  for (int k = i; k < 139264; k += stride) cst(eh + k, 0.f);
  for (int k = i; k < 262144; k += stride) cst(ynh + k, 0.f);
  for (int k = i; k < 8192; k += stride) cst(uh0 + k, 0.f);  // 64 pad rows
  for (int k = i; k < NWG * 32; k += stride) cstu(arr + k, 0u);
  for (int k = i; k < NGRP * 32; k += stride) cstu(grp + k, 0u);
  if (i < 512) cst(dbnd + i, x0[i]);
}

// ---------------------------------------------------------------------------
// Persistent main loop: 131 phases x ONE hierarchical barrier. T=8*ph.
//   bid   0..127 SC : e[Ty+r] += W[r-s]·y_nat[Ty+s], Ty=T-8   (y block ph-1)
//   bid 128..143 Yd : y_nat[T+s] += CA[s] d_T                 (block ph)
//   bid 144..150 Yu : y_nat[T+s] += sum_m CAB33[m] u[T+s-m-34]
//   bid 151..158 Wd : e[T+s]     += W0CA[s] d_T
//   bid 159..165 Wu : e[T+s]     += sum_m W0CAB33[m] u[T+s-m-34]
//   bid 166..181 Dt : dbnd[ph+1] = A8 d_T + sum_m AB33[m] u[T-26-m]
//   bid 182..213 Xp : x[Tq+s] += P[s+1] x[Tq-1], Tq=T-16      (block ph-2)
//   bid 214..229 Xr : x[Tq+s] += sum_i Rn[i] e[Tq+s-1-i]
//   bid 230..237 U  : u[Tu+s] = e[Tu+s] - KC x[Tu+s], Tu=T-24 (block ph-3)
// ---------------------------------------------------------------------------
__global__ __launch_bounds__(TPB, 1) void main_kernel(
    const float* __restrict__ B, const float* __restrict__ C,
    const float* __restrict__ x0, const float* __restrict__ Wfir,
    const float* __restrict__ KC, const float* __restrict__ W0C,
    const float* __restrict__ Pp, const float* __restrict__ CAp,
    const float* __restrict__ W0CAp, const float* __restrict__ Rnp,
    const float* __restrict__ AB33p, const float* __restrict__ CAB33p,
    const float* __restrict__ W0CAB33p, const float* __restrict__ A8k,
    float* __restrict__ xh, float* __restrict__ uh0, float* __restrict__ eh,
    float* __restrict__ ynh, float* __restrict__ dbnd,
    unsigned* __restrict__ arr, unsigned* __restrict__ grp) {
  __shared__ float smA[64 * 256];  // SC: Wfir c-slice [j][q], row 0 = zeros
  __shared__ float smY[8 * 256];   // SC: y block
  __shared__ float smV[512];       // d / x seed (broadcast-read)
  __shared__ float smW[8 * 128];   // u / e window
  __shared__ float smVx[8 * 516];  // U: 8 x-vectors (padded stride)
  __shared__ float redsc[4][16];
  const int bid = blockIdx.x;
  const int tid = threadIdx.x;

  if (bid < SC_N) {
    for (int i = tid; i < 16384; i += TPB) {
      int j = i >> 8;
      smA[i] = (j >= 1) ? Wfir[(size_t)j * 32768 + bid * 256 + (i & 255)] : 0.f;
    }
  }
  __syncthreads();

#pragma unroll 1
  for (int ph = 0; ph <= 130; ++ph) {
    const int T = ph * 8;

    if (bid < SC_N) {  // ---- SC ----
      if (ph >= 1 && ph < 129) {
        const int Ty = T - 8;
        const int c = bid;
        for (int i2 = tid; i2 < 1024; i2 += TPB) {
          float2 v = cld2(ynh + (size_t)Ty * 256 + 2 * i2);
          smY[2 * i2] = v.x;
          smY[2 * i2 + 1] = v.y;
        }
        __syncthreads();
        const int q = tid;
        float yreg[8];
#pragma unroll
        for (int s = 0; s < 8; ++s) yreg[s] = smY[s * 256 + q];
        const int wv = tid >> 6;
        const int lane = tid & 63;
#pragma unroll
        for (int kt = 0; kt < 5; ++kt) {
          const int r0 = 1 + 16 * kt;
          float wreg[23];
#pragma unroll
          for (int i = 0; i < 23; ++i) {
            const int j = r0 - 7 + i;
            wreg[i] = (j >= 1 && j <= 63) ? smA[j * 256 + q] : 0.f;
          }
          float acc[16];
#pragma unroll
          for (int a = 0; a < 16; ++a) acc[a] = 0.f;
#pragma unroll
          for (int a = 0; a < 16; ++a)
#pragma unroll
            for (int s = 0; s < 8; ++s) acc[a] += wreg[a + 7 - s] * yreg[s];
#pragma unroll
          for (int a = 0; a < 16; ++a) {
            float v = acc[a];
            v += __shfl_xor(v, 32);
            v += __shfl_xor(v, 16);
            v += __shfl_xor(v, 8);
            v += __shfl_xor(v, 4);
            v += __shfl_xor(v, 2);
            v += __shfl_xor(v, 1);
            if (lane == 0) redsc[wv][a] = v;
          }
          __syncthreads();
          if (tid < 16) {
            const int r = r0 + tid;
            if (r <= 70) {
              float sum = redsc[0][tid] + redsc[1][tid] + redsc[2][tid] + redsc[3][tid];
              atomicAdd(&eh[(size_t)(Ty + r) * 128 + c], sum);
            }
          }
          __syncthreads();
        }
      }
    } else if (bid < YU0) {  // ---- Yd ----
      if (ph < 128) {
        const int r = bid - YD0;
        const int s = r >> 1;
        const int half = (r & 1) << 7;
        {
          float2 v = cld2(dbnd + (size_t)ph * 512 + 2 * tid);
          smV[2 * tid] = v.x;
          smV[2 * tid + 1] = v.y;
        }
        __syncthreads();
        const float* Mrow = (s == 0) ? C : (CAp + (size_t)(s - 1) * 131072);
        const int row = half + (tid >> 1);
        const int seg = tid & 1;
        const float4* m4 = (const float4*)(Mrow + (size_t)row * 512 + seg * 256);
        const float4* v4 = (const float4*)(smV + seg * 256);
        float a = 0.f;
#pragma unroll
        for (int it = 0; it < 64; ++it) {
          float4 mm = m4[it], vv = v4[it];
          a += mm.x * vv.x + mm.y * vv.y + mm.z * vv.z + mm.w * vv.w;
        }
        a += __shfl_down(a, 1);
        if (seg == 0) atomicAdd(&ynh[(size_t)(T + s) * 256 + row], a);
        __syncthreads();
      }
    } else if (bid < WD0) {  // ---- Yu ----
      if (ph < 128) {
        const int m = bid - YU0;
        for (int i2 = tid; i2 < 512; i2 += TPB) {
          float2 v = cld2(uh0 + (size_t)(64 + T - 33) * 128 + 2 * i2);
          smW[2 * i2] = v.x;
          smW[2 * i2 + 1] = v.y;
        }
        __syncthreads();
        const int row = tid;  // 256 rows
        const float4* m4 = (const float4*)(CAB33p + (size_t)m * 32768 + (size_t)row * 128);
        for (int s = m + 1; s < 8; ++s) {
          const float4* u4 = (const float4*)(smW + (s - m - 1) * 128);
          float a = 0.f;
#pragma unroll
          for (int it = 0; it < 32; ++it) {
            float4 mm = m4[it], vv = u4[it];
            a += mm.x * vv.x + mm.y * vv.y + mm.z * vv.z + mm.w * vv.w;
          }
          atomicAdd(&ynh[(size_t)(T + s) * 256 + row], a);
        }
        __syncthreads();
      }
    } else if (bid < WU0) {  // ---- Wd ----
      if (ph < 128) {
        const int s = bid - WD0;
        {
          float2 v = cld2(dbnd + (size_t)ph * 512 + 2 * tid);
          smV[2 * tid] = v.x;
          smV[2 * tid + 1] = v.y;
        }
        __syncthreads();
        const float* Mrow = (s == 0) ? W0C : (W0CAp + (size_t)(s - 1) * 65536);
        const int row = tid >> 1;
        const int seg = tid & 1;
        const float4* m4 = (const float4*)(Mrow + (size_t)row * 512 + seg * 256);
        const float4* v4 = (const float4*)(smV + seg * 256);
        float a = 0.f;
#pragma unroll
        for (int it = 0; it < 64; ++it) {
          float4 mm = m4[it], vv = v4[it];
          a += mm.x * vv.x + mm.y * vv.y + mm.z * vv.z + mm.w * vv.w;
        }
        a += __shfl_down(a, 1);
        if (seg == 0) atomicAdd(&eh[(size_t)(T + s) * 128 + row], a);
        __syncthreads();
      }
    } else if (bid < DT0) {  // ---- Wu ----
      if (ph < 128) {
        const int m = bid - WU0;
        for (int i2 = tid; i2 < 512; i2 += TPB) {
          float2 v = cld2(uh0 + (size_t)(64 + T - 33) * 128 + 2 * i2);
          smW[2 * i2] = v.x;
          smW[2 * i2 + 1] = v.y;
        }
        __syncthreads();
        const int row = tid >> 1;
        const int seg = tid & 1;
        const float4* m4 = (const float4*)(W0CAB33p + (size_t)m * 16384 + (size_t)row * 128 + seg * 64);
        for (int s = m + 1; s < 8; ++s) {
          const float4* u4 = (const float4*)(smW + (s - m - 1) * 128 + seg * 64);
          float a = 0.f;
#pragma unroll
          for (int it = 0; it < 16; ++it) {
            float4 mm = m4[it], vv = u4[it];
            a += mm.x * vv.x + mm.y * vv.y + mm.z * vv.z + mm.w * vv.w;
          }
          a += __shfl_down(a, 1);
          if (seg == 0) atomicAdd(&eh[(size_t)(T + s) * 128 + row], a);
        }
        __syncthreads();
      }
    } else if (bid < XP0) {  // ---- Dt ----
      if (ph < 127) {
        const int g = bid - DT0;  // 0..15, 32 rows each
        {
          float2 v = cld2(dbnd + (size_t)ph * 512 + 2 * tid);
          smV[2 * tid] = v.x;
          smV[2 * tid + 1] = v.y;
        }
        for (int i2 = tid; i2 < 512; i2 += TPB) {
          float2 v = cld2(uh0 + (size_t)(64 + T - 33) * 128 + 2 * i2);
          smW[2 * i2] = v.x;
          smW[2 * i2 + 1] = v.y;
        }
        __syncthreads();
        const int row = g * 32 + (tid >> 3);
        const int l4 = tid & 7;
        float a = 0.f;
        {
          const float4* m4 = (const float4*)(A8k + (size_t)row * 512 + l4 * 64);
          const float4* v4 = (const float4*)(smV + l4 * 64);
#pragma unroll
          for (int it = 0; it < 16; ++it) {
            float4 mm = m4[it], vv = v4[it];
            a += mm.x * vv.x + mm.y * vv.y + mm.z * vv.z + mm.w * vv.w;
          }
        }
#pragma unroll
        for (int m = 0; m < 8; ++m) {
          const float4* m4 = (const float4*)(AB33p + (size_t)m * 65536 + (size_t)row * 128 + l4 * 16);
          const float4* v4 = (const float4*)(smW + (7 - m) * 128 + l4 * 16);
#pragma unroll
          for (int it = 0; it < 4; ++it) {
            float4 mm = m4[it], vv = v4[it];
            a += mm.x * vv.x + mm.y * vv.y + mm.z * vv.z + mm.w * vv.w;
          }
        }
        a += __shfl_down(a, 4);
        a += __shfl_down(a, 2);
        a += __shfl_down(a, 1);
        if (l4 == 0) cst(&dbnd[(size_t)(ph + 1) * 512 + row], a);
        __syncthreads();
      }
    } else if (bid < XR0) {  // ---- Xp ----
      if (ph >= 2 && ph < 130) {
        const int Tq = T - 16;
        const int r = bid - XP0;       // 0..31
        const int s = r >> 2;          // 0..7
        const int qtr = (r & 3) << 7;  // 128-row quarter
        {
          const float* src = (ph == 2) ? x0 : (xh + (size_t)(Tq - 1) * 512);
          float2 v = cld2(src + 2 * tid);
          smV[2 * tid] = v.x;
          smV[2 * tid + 1] = v.y;
        }
        __syncthreads();
        const int pslot = (ph == 2) ? s : (s + 1);
        const int row = qtr + (tid >> 1);
        const int seg = tid & 1;
        if (pslot == 0) {
          if (seg == 0) atomicAdd(&xh[(size_t)Tq * 512 + row], smV[row]);
        } else {
          const float4* m4 = (const float4*)(Pp + (size_t)(pslot - 1) * 262144 +
                                             (size_t)row * 512 + seg * 256);
          const float4* v4 = (const float4*)(smV + seg * 256);
          float a = 0.f;
#pragma unroll
          for (int it = 0; it < 64; ++it) {
            float4 mm = m4[it], vv = v4[it];
            a += mm.x * vv.x + mm.y * vv.y + mm.z * vv.z + mm.w * vv.w;
          }
          a += __shfl_down(a, 1);
          if (seg == 0) atomicAdd(&xh[(size_t)(Tq + s) * 512 + row], a);
        }
        __syncthreads();
      }
    } else if (bid < U0) {  // ---- Xr ----
      if (ph >= 2 && ph < 130) {
        const int Tq = T - 16;
        const int r = bid - XR0;
        const int i = r >> 1;
        const int half = (r & 1) << 8;
        for (int i2 = tid; i2 < 512; i2 += TPB) {
          int idx = 2 * i2;
          float2 v;
          if (ph == 2 && idx < 128) {
            v.x = 0.f;
            v.y = 0.f;
          } else {
            v = cld2(eh + (size_t)(Tq - 1) * 128 + idx);
          }
          smW[idx] = v.x;
          smW[idx + 1] = v.y;
        }
        __syncthreads();
        const int row = half + tid;
        const float* Rrow = (i == 0) ? (B + (size_t)row * 128)
                                     : (Rnp + (size_t)(i - 1) * 65536 + (size_t)row * 128);
        const float4* m4 = (const float4*)Rrow;
        for (int s = i; s < 8; ++s) {
          const float4* e4 = (const float4*)(smW + (s - i) * 128);
          float a = 0.f;
#pragma unroll
          for (int it = 0; it < 32; ++it) {
            float4 mm = m4[it], vv = e4[it];
            a += mm.x * vv.x + mm.y * vv.y + mm.z * vv.z + mm.w * vv.w;
          }
          atomicAdd(&xh[(size_t)(Tq + s) * 512 + row], a);
        }
        __syncthreads();
      }
    } else {  // ---- U (bid 230..237) ----
      if (ph >= 3) {
        const int Tu = T - 24;
        const int g = bid - U0;
        for (int i2 = tid; i2 < 2048; i2 += TPB) {
          int idx = 2 * i2;
          int rr = idx >> 9;
          int cc = idx & 511;
          float2 v = cld2(xh + (size_t)(Tu + rr) * 512 + cc);
          smVx[rr * 516 + cc] = v.x;
          smVx[rr * 516 + cc + 1] = v.y;
        }
        __syncthreads();
        const int o = tid >> 1;
        const int par = tid & 1;
        const int s = o >> 4;
        const int lr = o & 15;
        const int row = g * 16 + lr;
        const float4* m4 = (const float4*)(KC + (size_t)row * 512 + par * 256);
        const float4* v4 = (const float4*)(smVx + s * 516 + par * 256);
        float a = 0.f;
#pragma unroll
        for (int it = 0; it < 64; ++it) {
          float4 mm = m4[it], vv = v4[it];
          a += mm.x * vv.x + mm.y * vv.y + mm.z * vv.z + mm.w * vv.w;
        }
        a += __shfl_down(a, 1);
        if (par == 0) {
          float u = cld(&eh[(size_t)(Tu + s) * 128 + row]) - a;
          cst(&uh0[(size_t)(64 + Tu + s) * 128 + row], u);
        }
        __syncthreads();
      }
    }

    grid_barrier(arr, grp, bid, tid, (unsigned)(ph + 1));
  }
}

// ---------------------------------------------------------------------------
// Epilogue: y_obs_t = C x_t; cost_t = y'Q y + u'R u.  (one WG per t)
// ---------------------------------------------------------------------------
__global__ __launch_bounds__(256) void cost_kernel(const float* __restrict__ C,
    const float* __restrict__ Q, const float* __restrict__ R,
    const float* __restrict__ xh, const float* __restrict__ uh0,
    float* __restrict__ out) {
  __shared__ float xs[512];
  __shared__ float ys[256];
  __shared__ float us[128];
  __shared__ float redw[4];
  const int t = blockIdx.x;
  const int tid = threadIdx.x;
  {
    float2 v = cld2(xh + (size_t)t * 512 + 2 * tid);
    xs[2 * tid] = v.x;
    xs[2 * tid + 1] = v.y;
  }
  if (tid < 64) {
    float2 v = cld2(uh0 + (size_t)(64 + t) * 128 + 2 * tid);
    us[2 * tid] = v.x;
    us[2 * tid + 1] = v.y;
  }
  __syncthreads();
  {
    const float4* m4 = (const float4*)(C + (size_t)tid * 512);
    const float4* v4 = (const float4*)xs;
    float a = 0.f;
    for (int it = 0; it < 128; ++it) {
      float4 mm = m4[it], vv = v4[it];
      a += mm.x * vv.x + mm.y * vv.y + mm.z * vv.z + mm.w * vv.w;
    }
    ys[tid] = a;
  }
  __syncthreads();
  float acc;
  {
    const float* Qr = Q + (size_t)tid * 256;
    float qy = 0.f;
    for (int k = 0; k < 256; ++k) qy = fmaf(Qr[k], ys[k], qy);
    acc = qy * ys[tid];
  }
  if (tid < 128) {
    const float* Rr = R + (size_t)tid * 128;
    float ru = 0.f;
    for (int k = 0; k < 128; ++k) ru = fmaf(Rr[k], us[k], ru);
    acc += ru * us[tid];
  }
  float v = acc;
  v += __shfl_xor(v, 32);
  v += __shfl_xor(v, 16);
  v += __shfl_xor(v, 8);
  v += __shfl_xor(v, 4);
  v += __shfl_xor(v, 2);
  v += __shfl_xor(v, 1);
  if ((tid & 63) == 0) redw[tid >> 6] = v;
  __syncthreads();
  if (tid == 0) out[t] = redw[0] + redw[1] + redw[2] + redw[3];
}

// ---------------------------------------------------------------------------
extern "C" void kernel_launch(void* const* d_in, const int* in_sizes, int n_in,
                              void* d_out, int out_size, void* d_ws, size_t ws_size,
                              hipStream_t stream) {
  (void)in_sizes; (void)n_in; (void)out_size; (void)ws_size;
  const float* A = (const float*)d_in[0];
  const float* B = (const float*)d_in[1];
  const float* C = (const float*)d_in[2];
  const float* Q = (const float*)d_in[3];
  const float* R = (const float*)d_in[4];
  const float* Km = (const float*)d_in[5];
  const float* MT = (const float*)d_in[6];
  const float* Phi = (const float*)d_in[7];
  const float* sm = (const float*)d_in[8];
  const float* x0 = (const float*)d_in[9];

  float* ws = (float*)d_ws;
  // ---- ws layout (float offsets) ----
  const int oWfir = 0;               // 2,097,152
  const int oKC = 2097152;           // 65,536
  const int oW0C = 2162688;          // 65,536
  const int oAcl = 2228224;          // 262,144
  const int oP = 2490368;            // 8 x 262144  (P[1..8])
  const int oCA = 4587520;           // 7 x 131072  (CA[1..7])
  const int oW0CA = 5505024;         // 7 x 65536   (W0CA[1..7])
  const int oRn = 5963776;           // 7 x 65536   (Rn[1..7])
  const int oApB = 6422528;          // 8 x 65536   (ApB[1..8])
  const int oAB33 = 6946816;         // 8 x 65536   (AB33[0..7])
  const int oCAB33 = 7471104;        // 7 x 32768
  const int oW0CAB33 = 7700480;      // 7 x 16384
  const int oA2 = 7815168;           // 262,144
  const int oA4 = 8077312;
  const int oA8 = 8339456;
  const int oA16 = 8601600;
  const int oA32 = 8863744;
  const int oM2 = 9125888;           // 1,048,576 (BKC aliases after wfir)
  const int oBKC = oM2;
  const int oxh = 10174464;          // 524,288
  const int ouh0 = 10698752;         // 139,264  ((64+1024)x128)
  const int oeh = 10838016;          // 139,264  (1088x128)
  const int oynh = 10977280;         // 262,144
  const int odbnd = 11239424;        // 131x512 = 67,072
  const int oarr = 11306496;         // NWG*32 u32
  const int ogrp = oarr + NWG * 32;  // NGRP*32 u32

  float* xh = ws + oxh;
  float* uh0 = ws + ouh0;
  float* eh = ws + oeh;
  float* ynh = ws + oynh;
  float* dbnd = ws + odbnd;
  unsigned* arr = (unsigned*)(ws + oarr);
  unsigned* grp = (unsigned*)(ws + ogrp);

  JobBatch jb;
  jb.n = 0;
  jb.start[0] = 0;
  auto J = [&](int xs_, int xo, int ys_, int yo, int zo, int M, int N, int K) {
    int i = jb.n++;
    jb.xsel[i] = xs_; jb.xoff[i] = xo; jb.ysel[i] = ys_; jb.yoff[i] = yo;
    jb.zoff[i] = zo; jb.M[i] = M; jb.N[i] = N; jb.K[i] = K;
    jb.start[i + 1] = jb.start[i] + (M >> 6) * (N >> 6);
  };
  auto L = [&]() {
    multi_gemm<<<dim3(jb.start[jb.n]), dim3(256), 0, stream>>>(jb, A, B, C, Km, ws);
    jb.n = 0;
    jb.start[0] = 0;
  };

  init_kernel<<<dim3(2048), dim3(256), 0, stream>>>(x0, xh, eh, ynh, uh0, dbnd,
                                                    arr, grp);
  m2_kernel<<<dim3(4096), dim3(256), 0, stream>>>(MT, sm, ws + oM2);
  wfir_kernel<<<dim3(8192), dim3(256), 0, stream>>>(ws + oM2, Phi, ws + oWfir);

  // ---- L1 ----
  J(4, 0, 3, 0, oKC, 128, 512, 256);          // KC = Km@C
  J(1, 0, 1, 0, oA2, 512, 512, 512);          // A2
  J(1, 0, 2, 0, oApB, 512, 128, 512);         // ApB1 = A@B
  J(3, 0, 1, 0, oCA, 256, 512, 512);          // CA1 = C@A
  L();
  // ---- L2 ----
  J(2, 0, 0, oKC, oBKC, 512, 512, 128);       // BKC
  J(0, oA2, 0, oA2, oA4, 512, 512, 512);      // A4
  J(0, oCA, 1, 0, oCA + 131072, 256, 512, 512);      // CA2
  J(1, 0, 0, oApB, oApB + 65536, 512, 128, 512);     // ApB2
  J(0, oWfir, 3, 0, oW0C, 128, 512, 256);     // W0C = W[0]@C
  L();
  axpy_acl<<<dim3(1024), dim3(256), 0, stream>>>(A, ws + oBKC, ws + oAcl, ws + oP);
  // ---- L3 ----
  J(0, oA4, 0, oA4, oA8, 512, 512, 512);                          // A8
  J(0, oP, 0, oP, oP + 262144, 512, 512, 512);                    // P2
  J(0, oCA, 0, oA2, oCA + 2 * 131072, 256, 512, 512);             // CA3
  J(0, oCA + 131072, 0, oA2, oCA + 3 * 131072, 256, 512, 512);    // CA4
  J(0, oW0C, 1, 0, oW0CA, 128, 512, 512);                         // W0CA1
  J(0, oW0C, 0, oA2, oW0CA + 65536, 128, 512, 512);               // W0CA2
  J(0, oA2, 0, oApB, oApB + 2 * 65536, 512, 128, 512);            // ApB3
  J(0, oA2, 0, oApB + 65536, oApB + 3 * 65536, 512, 128, 512);    // ApB4
  L();
  // ---- L4 ----
  J(0, oA8, 0, oA8, oA16, 512, 512, 512);                         // A16
  J(0, oP, 0, oP + 262144, oP + 2 * 262144, 512, 512, 512);       // P3
  J(0, oP + 262144, 0, oP + 262144, oP + 3 * 262144, 512, 512, 512);  // P4
  for (int i = 1; i <= 3; ++i)                                    // CA5..CA7
    J(0, oCA + (i - 1) * 131072, 0, oA4, oCA + (i + 3) * 131072, 256, 512, 512);
  for (int i = 1; i <= 2; ++i)                                    // W0CA3,4
    J(0, oW0CA + (i - 1) * 65536, 0, oA2, oW0CA + (i + 1) * 65536, 128, 512, 512);
  for (int k = 1; k <= 4; ++k)                                    // ApB5..8
    J(0, oA4, 0, oApB + (k - 1) * 65536, oApB + (k + 3) * 65536, 512, 128, 512);
  J(0, oP, 2, 0, oRn, 512, 128, 512);                             // Rn1
  J(0, oP + 262144, 2, 0, oRn + 65536, 512, 128, 512);            // Rn2
  L();
  // ---- L5 ----
  J(0, oA16, 0, oA16, oA32, 512, 512, 512);                       // A32
  for (int i = 1; i <= 4; ++i)                                    // P5..P8 = P[i]@P4
    J(0, oP + (i - 1) * 262144, 0, oP + 3 * 262144, oP + (i + 3) * 262144, 512, 512, 512);
  for (int i = 1; i <= 3; ++i)                                    // W0CA5..7
    J(0, oW0CA + (i - 1) * 65536, 0, oA4, oW0CA + (i + 3) * 65536, 128, 512, 512);
  J(0, oP + 2 * 262144, 2, 0, oRn + 2 * 65536, 512, 128, 512);    // Rn3
  J(0, oP + 3 * 262144, 2, 0, oRn + 3 * 65536, 512, 128, 512);    // Rn4
  L();
  // ---- L6 ----
  for (int m = 0; m <= 7; ++m)                                    // AB33[0..7]
    J(0, oA32, 0, oApB + m * 65536, oAB33 + m * 65536, 512, 128, 512);
  for (int i = 5; i <= 7; ++i)                                    // Rn5..7
    J(0, oP + (i - 1) * 262144, 2, 0, oRn + (i - 1) * 65536, 512, 128, 512);
  L();
  // ---- L7 ----
  for (int m = 0; m <= 6; ++m)                                    // CAB33[0..6]
    J(3, 0, 0, oAB33 + m * 65536, oCAB33 + m * 32768, 256, 128, 512);
  for (int m = 0; m <= 6; ++m)                                    // W0CAB33[0..6]
    J(0, oW0C, 0, oAB33 + m * 65536, oW0CAB33 + m * 16384, 128, 128, 512);
  L();

  main_kernel<<<dim3(NWG), dim3(TPB), 0, stream>>>(
      B, C, x0, ws + oWfir, ws + oKC, ws + oW0C, ws + oP, ws + oCA,
      ws + oW0CA, ws + oRn, ws + oAB33, ws + oCAB33, ws + oW0CAB33,
      ws + oA8, xh, uh0, eh, ynh, dbnd, arr, grp);

  cost_kernel<<<dim3(1024), dim3(256), 0, stream>>>(C, Q, R, xh, uh0,
                                                    (float*)d_out);
}

// Round 9
// 3352.937 us; speedup vs baseline: 1.0055x; 1.0055x over previous
//
#include <hip/hip_runtime.h>

#define TPB 256
#define MAXJ 48

// role bases
#define SC_N 128
#define YD0 128
#define YU0 144
#define WD0 151
#define WU0 159
#define DT0 166
#define XP0 182
#define XR0 214
#define U0 230
#define NWG 238
#define NGRP 8
#define GCH 30  // ceil(NWG/NGRP)

// ---------------------------------------------------------------------------
// Coherent (agent-scope, MALL-served) helpers: sc1 loads/stores, no fences.
// ---------------------------------------------------------------------------
__device__ __forceinline__ void cst(float* p, float v) {
  __hip_atomic_store(p, v, __ATOMIC_RELAXED, __HIP_MEMORY_SCOPE_AGENT);
}
__device__ __forceinline__ void cstu(unsigned* p, unsigned v) {
  __hip_atomic_store(p, v, __ATOMIC_RELAXED, __HIP_MEMORY_SCOPE_AGENT);
}
__device__ __forceinline__ unsigned cldu(const unsigned* p) {
  return __hip_atomic_load(p, __ATOMIC_RELAXED, __HIP_MEMORY_SCOPE_AGENT);
}
__device__ __forceinline__ float cld(const float* p) {
  return __hip_atomic_load(p, __ATOMIC_RELAXED, __HIP_MEMORY_SCOPE_AGENT);
}
__device__ __forceinline__ float2 cld2(const float* p) {
  unsigned long long u = __hip_atomic_load(
      reinterpret_cast<const unsigned long long*>(p), __ATOMIC_RELAXED,
      __HIP_MEMORY_SCOPE_AGENT);
  float2 v;
  __builtin_memcpy(&v, &u, 8);
  return v;
}

// ---------------------------------------------------------------------------
// Hierarchical grid barrier (R8): arrival flag/WG, 8 checkers, 8 group flags.
// ---------------------------------------------------------------------------
__device__ __forceinline__ void grid_barrier(unsigned* __restrict__ arr,
                                             unsigned* __restrict__ grp,
                                             int bid, int tid, unsigned phase) {
  asm volatile("s_waitcnt vmcnt(0)" ::: "memory");
  __syncthreads();
  if (tid == 0) cstu(arr + (bid << 5), phase);
  if (bid < NGRP) {
    const int lo = bid * GCH;
    const int n = (NWG - lo < GCH) ? (NWG - lo) : GCH;
    if (tid < n) {
      while (cldu(arr + ((lo + tid) << 5)) < phase) __builtin_amdgcn_s_sleep(1);
    }
    __syncthreads();
    if (tid == 0) cstu(grp + (bid << 5), phase);
  }
  if (tid < NGRP) {
    while (cldu(grp + (tid << 5)) < phase) __builtin_amdgcn_s_sleep(1);
  }
  __atomic_signal_fence(__ATOMIC_SEQ_CST);
  __syncthreads();
}

// ---------------------------------------------------------------------------
// Tiled fp32 GEMM tile body.
// ---------------------------------------------------------------------------
__device__ void gemm_tile(const float* __restrict__ X, const float* __restrict__ Y,
                          float* __restrict__ Z, int M, int N, int Kd,
                          int mtile, int ntile) {
  __shared__ float Xs[16][65];
  __shared__ float Ys[16][65];
  const int tx = threadIdx.x & 15;
  const int ty = threadIdx.x >> 4;
  const int mbase = mtile * 64;
  const int nbase = ntile * 64;
  float acc[4][4] = {};
  for (int k0 = 0; k0 < Kd; k0 += 16) {
#pragma unroll
    for (int r = 0; r < 4; ++r) {
      int idx = threadIdx.x + 256 * r;
      int mm = idx >> 4, kk = idx & 15;
      int gm = mbase + mm, gk = k0 + kk;
      Xs[kk][mm] = (gm < M && gk < Kd) ? X[(size_t)gm * Kd + gk] : 0.f;
      int nn = idx & 63, k2 = idx >> 6;
      int gn = nbase + nn, gk2 = k0 + k2;
      Ys[k2][nn] = (gk2 < Kd && gn < N) ? Y[(size_t)gk2 * N + gn] : 0.f;
    }
    __syncthreads();
#pragma unroll
    for (int kk = 0; kk < 16; ++kk) {
      float xv[4], yv[4];
#pragma unroll
      for (int a = 0; a < 4; ++a) xv[a] = Xs[kk][ty * 4 + a];
#pragma unroll
      for (int b = 0; b < 4; ++b) yv[b] = Ys[kk][tx * 4 + b];
#pragma unroll
      for (int a = 0; a < 4; ++a)
#pragma unroll
        for (int b = 0; b < 4; ++b) acc[a][b] += xv[a] * yv[b];
    }
    __syncthreads();
  }
#pragma unroll
  for (int a = 0; a < 4; ++a) {
    int gm = mbase + ty * 4 + a;
    if (gm < M) {
#pragma unroll
      for (int b = 0; b < 4; ++b) {
        int gn = nbase + tx * 4 + b;
        if (gn < N) Z[(size_t)gm * N + gn] = acc[a][b];
      }
    }
  }
}

struct JobBatch {
  int n;
  int start[MAXJ + 1];
  int xsel[MAXJ], xoff[MAXJ], ysel[MAXJ], yoff[MAXJ], zoff[MAXJ];
  int M[MAXJ], N[MAXJ], K[MAXJ];
};

__global__ __launch_bounds__(256) void multi_gemm(JobBatch jb,
    const float* __restrict__ A, const float* __restrict__ Bm,
    const float* __restrict__ C, const float* __restrict__ Km,
    float* __restrict__ ws) {
  int b = blockIdx.x;
  int j = 0;
  while (j < jb.n - 1 && b >= jb.start[j + 1]) ++j;
  int rel = b - jb.start[j];
  const float* bases[5] = {ws, A, Bm, C, Km};
  const float* X = bases[jb.xsel[j]] + jb.xoff[j];
  const float* Y = bases[jb.ysel[j]] + jb.yoff[j];
  float* Z = ws + jb.zoff[j];
  int tn = jb.N[j] >> 6;
  gemm_tile(X, Y, Z, jb.M[j], jb.N[j], jb.K[j], rel / tn, rel % tn);
}

// ---------------------------------------------------------------------------
__global__ __launch_bounds__(256) void m2_kernel(const float* __restrict__ MT,
    const float* __restrict__ sm, float* __restrict__ M2g) {
  int idx = blockIdx.x * 256 + threadIdx.x;
  if (idx >= 128 * 32 * 256) return;
  int q = idx & 255;
  int ci = idx >> 8;
  const float* base = MT + (size_t)ci * 32 * 256 + q;
  float acc = 0.f;
#pragma unroll
  for (int j = 0; j < 32; ++j) acc += base[j * 256] * sm[j];
  M2g[idx] = acc;
}

__global__ __launch_bounds__(256) void wfir_kernel(const float* __restrict__ M2g,
    const float* __restrict__ Phi, float* __restrict__ W) {
  int idx = blockIdx.x * 256 + threadIdx.x;  // j*32768 + c*256 + q
  if (idx >= 64 * 32768) return;
  int j = idx >> 15;
  int cq = idx & 32767;
  int c = cq >> 8;
  int q = cq & 255;
  float acc = 0.f;
#pragma unroll
  for (int i = 0; i < 32; ++i)
    acc = fmaf(Phi[(i << 6) | j], M2g[(size_t)(((c << 5) | i) << 8) | q], acc);
  W[idx] = acc;
}

__global__ __launch_bounds__(256) void axpy_acl(const float* __restrict__ A,
    const float* __restrict__ BKC, float* __restrict__ Acl, float* __restrict__ P1) {
  int i = blockIdx.x * 256 + threadIdx.x;
  if (i < 262144) {
    float v = A[i] - BKC[i];
    Acl[i] = v;
    P1[i] = v;
  }
}

// ---------------------------------------------------------------------------
__global__ void init_kernel(const float* __restrict__ x0, float* __restrict__ xh,
    float* __restrict__ eh, float* __restrict__ ynh, float* __restrict__ uh0,
    float* __restrict__ dbnd, unsigned* __restrict__ arr,
    unsigned* __restrict__ grp) {
  int i = blockIdx.x * 256 + threadIdx.x;
  int stride = gridDim.x * 256;
  for (int k = i; k < 524288; k += stride) cst(xh + k, 0.f);
  for (int k = i; k < 139264; k += stride) cst(eh + k, 0.f);
  for (int k = i; k < 262144; k += stride) cst(ynh + k, 0.f);
  for (int k = i; k < 8192; k += stride) cst(uh0 + k, 0.f);
  for (int k = i; k < NWG * 32; k += stride) cstu(arr + k, 0u);
  for (int k = i; k < NGRP * 32; k += stride) cstu(grp + k, 0u);
  if (i < 512) cst(dbnd + i, x0[i]);
}

// ---------------------------------------------------------------------------
// Persistent main loop, one branch per role, each with its own 131-phase loop
// and register-pinned map rows (phase-invariant). Lag schedule as R8:
//   SC : e[Ty+r] += W[r-s]·y[Ty+s], Ty=T-8   Yd/Yu: y block T   Wd/Wu: e T
//   Dt : dbnd[ph+1]                          Xp/Xr: x block T-16
//   U  : u block T-24
// ---------------------------------------------------------------------------
__global__ __launch_bounds__(TPB, 1) void main_kernel(
    const float* __restrict__ B, const float* __restrict__ C,
    const float* __restrict__ x0, const float* __restrict__ Wfir,
    const float* __restrict__ KC, const float* __restrict__ W0C,
    const float* __restrict__ Pp, const float* __restrict__ CAp,
    const float* __restrict__ W0CAp, const float* __restrict__ Rnp,
    const float* __restrict__ AB33p, const float* __restrict__ CAB33p,
    const float* __restrict__ W0CAB33p, const float* __restrict__ A8k,
    float* __restrict__ xh, float* __restrict__ uh0, float* __restrict__ eh,
    float* __restrict__ ynh, float* __restrict__ dbnd,
    unsigned* __restrict__ arr, unsigned* __restrict__ grp) {
  __shared__ float smA[64 * 256];
  __shared__ float smY[8 * 256];
  __shared__ float smV[512];
  __shared__ float smW[8 * 128];
  __shared__ float smVx[8 * 516];
  __shared__ float redsc[4][16];
  const int bid = blockIdx.x;
  const int tid = threadIdx.x;

  if (bid < SC_N) {
    // ================= SC =================
    for (int i = tid; i < 16384; i += TPB) {
      int j = i >> 8;
      smA[i] = (j >= 1) ? Wfir[(size_t)j * 32768 + bid * 256 + (i & 255)] : 0.f;
    }
    __syncthreads();
#pragma unroll 1
    for (int ph = 0; ph <= 130; ++ph) {
      if (ph >= 1 && ph < 129) {
        const int Ty = ph * 8 - 8;
        const int c = bid;
        for (int i2 = tid; i2 < 1024; i2 += TPB) {
          float2 v = cld2(ynh + (size_t)Ty * 256 + 2 * i2);
          smY[2 * i2] = v.x;
          smY[2 * i2 + 1] = v.y;
        }
        __syncthreads();
        const int q = tid;
        float yreg[8];
#pragma unroll
        for (int s = 0; s < 8; ++s) yreg[s] = smY[s * 256 + q];
        const int wv = tid >> 6;
        const int lane = tid & 63;
#pragma unroll
        for (int kt = 0; kt < 5; ++kt) {
          const int r0 = 1 + 16 * kt;
          float wreg[23];
#pragma unroll
          for (int i = 0; i < 23; ++i) {
            const int j = r0 - 7 + i;
            wreg[i] = (j >= 1 && j <= 63) ? smA[j * 256 + q] : 0.f;
          }
          float acc[16];
#pragma unroll
          for (int a = 0; a < 16; ++a) acc[a] = 0.f;
#pragma unroll
          for (int a = 0; a < 16; ++a)
#pragma unroll
            for (int s = 0; s < 8; ++s) acc[a] += wreg[a + 7 - s] * yreg[s];
#pragma unroll
          for (int a = 0; a < 16; ++a) {
            float v = acc[a];
            v += __shfl_xor(v, 32);
            v += __shfl_xor(v, 16);
            v += __shfl_xor(v, 8);
            v += __shfl_xor(v, 4);
            v += __shfl_xor(v, 2);
            v += __shfl_xor(v, 1);
            if (lane == 0) redsc[wv][a] = v;
          }
          __syncthreads();
          if (tid < 16) {
            const int r = r0 + tid;
            if (r <= 70) {
              float sum = redsc[0][tid] + redsc[1][tid] + redsc[2][tid] + redsc[3][tid];
              atomicAdd(&eh[(size_t)(Ty + r) * 128 + bid], sum);
            }
          }
          __syncthreads();
        }
        (void)c;
      }
      grid_barrier(arr, grp, bid, tid, (unsigned)(ph + 1));
    }
  } else if (bid < YU0) {
    // ================= Yd =================
    const int r = bid - YD0;
    const int s = r >> 1;
    const int half = (r & 1) << 7;
    const int row = half + (tid >> 1);
    const int seg = tid & 1;
    const float* Mrow = (s == 0) ? C : (CAp + (size_t)(s - 1) * 131072);
    const float4* m4 = (const float4*)(Mrow + (size_t)row * 512 + seg * 256);
    float4 cm[64];
#pragma unroll
    for (int it = 0; it < 64; ++it) cm[it] = m4[it];
#pragma unroll 1
    for (int ph = 0; ph <= 130; ++ph) {
      if (ph < 128) {
        const int T = ph * 8;
        {
          float2 v = cld2(dbnd + (size_t)ph * 512 + 2 * tid);
          smV[2 * tid] = v.x;
          smV[2 * tid + 1] = v.y;
        }
        __syncthreads();
        const float4* v4 = (const float4*)(smV + seg * 256);
        float a = 0.f;
#pragma unroll
        for (int it = 0; it < 64; ++it) {
          float4 mm = cm[it], vv = v4[it];
          a += mm.x * vv.x + mm.y * vv.y + mm.z * vv.z + mm.w * vv.w;
        }
        a += __shfl_down(a, 1);
        if (seg == 0) atomicAdd(&ynh[(size_t)(T + s) * 256 + row], a);
      }
      grid_barrier(arr, grp, bid, tid, (unsigned)(ph + 1));
    }
  } else if (bid < WD0) {
    // ================= Yu =================
    const int m = bid - YU0;
    const int row = tid;
    const float4* m4 = (const float4*)(CAB33p + (size_t)m * 32768 + (size_t)row * 128);
    float4 cm[32];
#pragma unroll
    for (int it = 0; it < 32; ++it) cm[it] = m4[it];
#pragma unroll 1
    for (int ph = 0; ph <= 130; ++ph) {
      if (ph < 128) {
        const int T = ph * 8;
        for (int i2 = tid; i2 < 512; i2 += TPB) {
          float2 v = cld2(uh0 + (size_t)(64 + T - 33) * 128 + 2 * i2);
          smW[2 * i2] = v.x;
          smW[2 * i2 + 1] = v.y;
        }
        __syncthreads();
#pragma unroll
        for (int s = 1; s < 8; ++s) {
          if (s > m) {
            const float4* u4 = (const float4*)(smW + (s - m - 1) * 128);
            float a = 0.f;
#pragma unroll
            for (int it = 0; it < 32; ++it) {
              float4 mm = cm[it], vv = u4[it];
              a += mm.x * vv.x + mm.y * vv.y + mm.z * vv.z + mm.w * vv.w;
            }
            atomicAdd(&ynh[(size_t)(T + s) * 256 + row], a);
          }
        }
      }
      grid_barrier(arr, grp, bid, tid, (unsigned)(ph + 1));
    }
  } else if (bid < WU0) {
    // ================= Wd =================
    const int s = bid - WD0;
    const int row = tid >> 1;
    const int seg = tid & 1;
    const float* Mrow = (s == 0) ? W0C : (W0CAp + (size_t)(s - 1) * 65536);
    const float4* m4 = (const float4*)(Mrow + (size_t)row * 512 + seg * 256);
    float4 cm[64];
#pragma unroll
    for (int it = 0; it < 64; ++it) cm[it] = m4[it];
#pragma unroll 1
    for (int ph = 0; ph <= 130; ++ph) {
      if (ph < 128) {
        const int T = ph * 8;
        {
          float2 v = cld2(dbnd + (size_t)ph * 512 + 2 * tid);
          smV[2 * tid] = v.x;
          smV[2 * tid + 1] = v.y;
        }
        __syncthreads();
        const float4* v4 = (const float4*)(smV + seg * 256);
        float a = 0.f;
#pragma unroll
        for (int it = 0; it < 64; ++it) {
          float4 mm = cm[it], vv = v4[it];
          a += mm.x * vv.x + mm.y * vv.y + mm.z * vv.z + mm.w * vv.w;
        }
        a += __shfl_down(a, 1);
        if (seg == 0) atomicAdd(&eh[(size_t)(T + s) * 128 + row], a);
      }
      grid_barrier(arr, grp, bid, tid, (unsigned)(ph + 1));
    }
  } else if (bid < DT0) {
    // ================= Wu =================
    const int m = bid - WU0;
    const int row = tid >> 1;
    const int seg = tid & 1;
    const float4* m4 = (const float4*)(W0CAB33p + (size_t)m * 16384 + (size_t)row * 128 + seg * 64);
    float4 cm[16];
#pragma unroll
    for (int it = 0; it < 16; ++it) cm[it] = m4[it];
#pragma unroll 1
    for (int ph = 0; ph <= 130; ++ph) {
      if (ph < 128) {
        const int T = ph * 8;
        for (int i2 = tid; i2 < 512; i2 += TPB) {
          float2 v = cld2(uh0 + (size_t)(64 + T - 33) * 128 + 2 * i2);
          smW[2 * i2] = v.x;
          smW[2 * i2 + 1] = v.y;
        }
        __syncthreads();
#pragma unroll
        for (int s = 1; s < 8; ++s) {
          if (s > m) {
            const float4* u4 = (const float4*)(smW + (s - m - 1) * 128 + seg * 64);
            float a = 0.f;
#pragma unroll
            for (int it = 0; it < 16; ++it) {
              float4 mm = cm[it], vv = u4[it];
              a += mm.x * vv.x + mm.y * vv.y + mm.z * vv.z + mm.w * vv.w;
            }
            a += __shfl_down(a, 1);
            if (seg == 0) atomicAdd(&eh[(size_t)(T + s) * 128 + row], a);
          }
        }
      }
      grid_barrier(arr, grp, bid, tid, (unsigned)(ph + 1));
    }
  } else if (bid < XP0) {
    // ================= Dt ================= (k%8-interleaved caches)
    const int g = bid - DT0;
    const int row = g * 32 + (tid >> 3);
    const int l8 = tid & 7;
    float4 ca[16], cb[32];
    {
      const float4* m4 = (const float4*)(A8k + (size_t)row * 512);
#pragma unroll
      for (int it = 0; it < 16; ++it) ca[it] = m4[it * 8 + l8];
    }
#pragma unroll
    for (int m = 0; m < 8; ++m) {
      const float4* m4 = (const float4*)(AB33p + (size_t)m * 65536 + (size_t)row * 128);
#pragma unroll
      for (int it = 0; it < 4; ++it) cb[m * 4 + it] = m4[it * 8 + l8];
    }
#pragma unroll 1
    for (int ph = 0; ph <= 130; ++ph) {
      if (ph < 127) {
        const int T = ph * 8;
        {
          float2 v = cld2(dbnd + (size_t)ph * 512 + 2 * tid);
          smV[2 * tid] = v.x;
          smV[2 * tid + 1] = v.y;
        }
        for (int i2 = tid; i2 < 512; i2 += TPB) {
          float2 v = cld2(uh0 + (size_t)(64 + T - 33) * 128 + 2 * i2);
          smW[2 * i2] = v.x;
          smW[2 * i2 + 1] = v.y;
        }
        __syncthreads();
        const float4* v4 = (const float4*)smV;
        float a = 0.f;
#pragma unroll
        for (int it = 0; it < 16; ++it) {
          float4 mm = ca[it], vv = v4[it * 8 + l8];
          a += mm.x * vv.x + mm.y * vv.y + mm.z * vv.z + mm.w * vv.w;
        }
#pragma unroll
        for (int m = 0; m < 8; ++m) {
          const float4* w4 = (const float4*)(smW + (7 - m) * 128);
#pragma unroll
          for (int it = 0; it < 4; ++it) {
            float4 mm = cb[m * 4 + it], vv = w4[it * 8 + l8];
            a += mm.x * vv.x + mm.y * vv.y + mm.z * vv.z + mm.w * vv.w;
          }
        }
        a += __shfl_down(a, 4);
        a += __shfl_down(a, 2);
        a += __shfl_down(a, 1);
        if (l8 == 0) cst(&dbnd[(size_t)(ph + 1) * 512 + row], a);
      }
      grid_barrier(arr, grp, bid, tid, (unsigned)(ph + 1));
    }
  } else if (bid < XR0) {
    // ================= Xp =================
    const int r = bid - XP0;       // 0..31
    const int s = r >> 2;          // 0..7
    const int qtr = (r & 3) << 7;
    const int row = qtr + (tid >> 1);
    const int seg = tid & 1;
    const float4* mp = (const float4*)(Pp + (size_t)s * 262144 + (size_t)row * 512 + seg * 256);
    float4 cm[64];  // P[s+1]
#pragma unroll
    for (int it = 0; it < 64; ++it) cm[it] = mp[it];
#pragma unroll 1
    for (int ph = 0; ph <= 130; ++ph) {
      if (ph >= 2 && ph < 130) {
        const int Tq = ph * 8 - 16;
        {
          const float* src = (ph == 2) ? x0 : (xh + (size_t)(Tq - 1) * 512);
          float2 v = cld2(src + 2 * tid);
          smV[2 * tid] = v.x;
          smV[2 * tid + 1] = v.y;
        }
        __syncthreads();
        if (ph == 2) {
          if (s == 0) {
            if (seg == 0) atomicAdd(&xh[(size_t)Tq * 512 + row], smV[row]);
          } else {
            const float4* m4 = (const float4*)(Pp + (size_t)(s - 1) * 262144 +
                                               (size_t)row * 512 + seg * 256);
            const float4* v4 = (const float4*)(smV + seg * 256);
            float a = 0.f;
#pragma unroll
            for (int it = 0; it < 64; ++it) {
              float4 mm = m4[it], vv = v4[it];
              a += mm.x * vv.x + mm.y * vv.y + mm.z * vv.z + mm.w * vv.w;
            }
            a += __shfl_down(a, 1);
            if (seg == 0) atomicAdd(&xh[(size_t)(Tq + s) * 512 + row], a);
          }
        } else {
          const float4* v4 = (const float4*)(smV + seg * 256);
          float a = 0.f;
#pragma unroll
          for (int it = 0; it < 64; ++it) {
            float4 mm = cm[it], vv = v4[it];
            a += mm.x * vv.x + mm.y * vv.y + mm.z * vv.z + mm.w * vv.w;
          }
          a += __shfl_down(a, 1);
          if (seg == 0) atomicAdd(&xh[(size_t)(Tq + s) * 512 + row], a);
        }
      }
      grid_barrier(arr, grp, bid, tid, (unsigned)(ph + 1));
    }
  } else if (bid < U0) {
    // ================= Xr =================
    const int r = bid - XR0;  // 0..15
    const int i = r >> 1;
    const int half = (r & 1) << 8;
    const int row = half + tid;
    const float* Rrow = (i == 0) ? (B + (size_t)row * 128)
                                 : (Rnp + (size_t)(i - 1) * 65536 + (size_t)row * 128);
    const float4* m4 = (const float4*)Rrow;
    float4 cm[32];
#pragma unroll
    for (int it = 0; it < 32; ++it) cm[it] = m4[it];
#pragma unroll 1
    for (int ph = 0; ph <= 130; ++ph) {
      if (ph >= 2 && ph < 130) {
        const int Tq = ph * 8 - 16;
        for (int i2 = tid; i2 < 512; i2 += TPB) {
          int idx = 2 * i2;
          float2 v;
          if (ph == 2 && idx < 128) {
            v.x = 0.f;
            v.y = 0.f;
          } else {
            v = cld2(eh + (size_t)(Tq - 1) * 128 + idx);
          }
          smW[idx] = v.x;
          smW[idx + 1] = v.y;
        }
        __syncthreads();
#pragma unroll
        for (int s = 0; s < 8; ++s) {
          if (s >= i) {
            const float4* e4 = (const float4*)(smW + (s - i) * 128);
            float a = 0.f;
#pragma unroll
            for (int it = 0; it < 32; ++it) {
              float4 mm = cm[it], vv = e4[it];
              a += mm.x * vv.x + mm.y * vv.y + mm.z * vv.z + mm.w * vv.w;
            }
            atomicAdd(&xh[(size_t)(Tq + s) * 512 + row], a);
          }
        }
      }
      grid_barrier(arr, grp, bid, tid, (unsigned)(ph + 1));
    }
  } else {
    // ================= U =================
    const int g = bid - U0;
    const int o = tid >> 1;
    const int par = tid & 1;
    const int s = o >> 4;
    const int lr = o & 15;
    const int row = g * 16 + lr;
    const float4* m4 = (const float4*)(KC + (size_t)row * 512 + par * 256);
    float4 cm[64];
#pragma unroll
    for (int it = 0; it < 64; ++it) cm[it] = m4[it];
#pragma unroll 1
    for (int ph = 0; ph <= 130; ++ph) {
      if (ph >= 3) {
        const int Tu = ph * 8 - 24;
        for (int i2 = tid; i2 < 2048; i2 += TPB) {
          int idx = 2 * i2;
          int rr = idx >> 9;
          int cc = idx & 511;
          float2 v = cld2(xh + (size_t)(Tu + rr) * 512 + cc);
          smVx[rr * 516 + cc] = v.x;
          smVx[rr * 516 + cc + 1] = v.y;
        }
        __syncthreads();
        const float4* v4 = (const float4*)(smVx + s * 516 + par * 256);
        float a = 0.f;
#pragma unroll
        for (int it = 0; it < 64; ++it) {
          float4 mm = cm[it], vv = v4[it];
          a += mm.x * vv.x + mm.y * vv.y + mm.z * vv.z + mm.w * vv.w;
        }
        a += __shfl_down(a, 1);
        if (par == 0) {
          float u = cld(&eh[(size_t)(Tu + s) * 128 + row]) - a;
          cst(&uh0[(size_t)(64 + Tu + s) * 128 + row], u);
        }
      }
      grid_barrier(arr, grp, bid, tid, (unsigned)(ph + 1));
    }
  }
}

// ---------------------------------------------------------------------------
// Epilogue: y_obs_t = C x_t; cost_t = y'Q y + u'R u.  (one WG per t)
// ---------------------------------------------------------------------------
__global__ __launch_bounds__(256) void cost_kernel(const float* __restrict__ C,
    const float* __restrict__ Q, const float* __restrict__ R,
    const float* __restrict__ xh, const float* __restrict__ uh0,
    float* __restrict__ out) {
  __shared__ float xs[512];
  __shared__ float ys[256];
  __shared__ float us[128];
  __shared__ float redw[4];
  const int t = blockIdx.x;
  const int tid = threadIdx.x;
  {
    float2 v = cld2(xh + (size_t)t * 512 + 2 * tid);
    xs[2 * tid] = v.x;
    xs[2 * tid + 1] = v.y;
  }
  if (tid < 64) {
    float2 v = cld2(uh0 + (size_t)(64 + t) * 128 + 2 * tid);
    us[2 * tid] = v.x;
    us[2 * tid + 1] = v.y;
  }
  __syncthreads();
  {
    const float4* m4 = (const float4*)(C + (size_t)tid * 512);
    const float4* v4 = (const float4*)xs;
    float a = 0.f;
    for (int it = 0; it < 128; ++it) {
      float4 mm = m4[it], vv = v4[it];
      a += mm.x * vv.x + mm.y * vv.y + mm.z * vv.z + mm.w * vv.w;
    }
    ys[tid] = a;
  }
  __syncthreads();
  float acc;
  {
    const float* Qr = Q + (size_t)tid * 256;
    float qy = 0.f;
    for (int k = 0; k < 256; ++k) qy = fmaf(Qr[k], ys[k], qy);
    acc = qy * ys[tid];
  }
  if (tid < 128) {
    const float* Rr = R + (size_t)tid * 128;
    float ru = 0.f;
    for (int k = 0; k < 128; ++k) ru = fmaf(Rr[k], us[k], ru);
    acc += ru * us[tid];
  }
  float v = acc;
  v += __shfl_xor(v, 32);
  v += __shfl_xor(v, 16);
  v += __shfl_xor(v, 8);
  v += __shfl_xor(v, 4);
  v += __shfl_xor(v, 2);
  v += __shfl_xor(v, 1);
  if ((tid & 63) == 0) redw[tid >> 6] = v;
  __syncthreads();
  if (tid == 0) out[t] = redw[0] + redw[1] + redw[2] + redw[3];
}

// ---------------------------------------------------------------------------
extern "C" void kernel_launch(void* const* d_in, const int* in_sizes, int n_in,
                              void* d_out, int out_size, void* d_ws, size_t ws_size,
                              hipStream_t stream) {
  (void)in_sizes; (void)n_in; (void)out_size; (void)ws_size;
  const float* A = (const float*)d_in[0];
  const float* B = (const float*)d_in[1];
  const float* C = (const float*)d_in[2];
  const float* Q = (const float*)d_in[3];
  const float* R = (const float*)d_in[4];
  const float* Km = (const float*)d_in[5];
  const float* MT = (const float*)d_in[6];
  const float* Phi = (const float*)d_in[7];
  const float* sm = (const float*)d_in[8];
  const float* x0 = (const float*)d_in[9];

  float* ws = (float*)d_ws;
  const int oWfir = 0;
  const int oKC = 2097152;
  const int oW0C = 2162688;
  const int oAcl = 2228224;
  const int oP = 2490368;            // 8 x 262144  (P[1..8])
  const int oCA = 4587520;           // 7 x 131072  (CA[1..7])
  const int oW0CA = 5505024;         // 7 x 65536   (W0CA[1..7])
  const int oRn = 5963776;           // 7 x 65536   (Rn[1..7])
  const int oApB = 6422528;          // 8 x 65536   (ApB[1..8])
  const int oAB33 = 6946816;         // 8 x 65536   (AB33[0..7])
  const int oCAB33 = 7471104;        // 7 x 32768
  const int oW0CAB33 = 7700480;      // 7 x 16384
  const int oA2 = 7815168;
  const int oA4 = 8077312;
  const int oA8 = 8339456;
  const int oA16 = 8601600;
  const int oA32 = 8863744;
  const int oM2 = 9125888;
  const int oBKC = oM2;
  const int oxh = 10174464;
  const int ouh0 = 10698752;
  const int oeh = 10838016;
  const int oynh = 10977280;
  const int odbnd = 11239424;
  const int oarr = 11306496;
  const int ogrp = oarr + NWG * 32;

  float* xh = ws + oxh;
  float* uh0 = ws + ouh0;
  float* eh = ws + oeh;
  float* ynh = ws + oynh;
  float* dbnd = ws + odbnd;
  unsigned* arr = (unsigned*)(ws + oarr);
  unsigned* grp = (unsigned*)(ws + ogrp);

  JobBatch jb;
  jb.n = 0;
  jb.start[0] = 0;
  auto J = [&](int xs_, int xo, int ys_, int yo, int zo, int M, int N, int K) {
    int i = jb.n++;
    jb.xsel[i] = xs_; jb.xoff[i] = xo; jb.ysel[i] = ys_; jb.yoff[i] = yo;
    jb.zoff[i] = zo; jb.M[i] = M; jb.N[i] = N; jb.K[i] = K;
    jb.start[i + 1] = jb.start[i] + (M >> 6) * (N >> 6);
  };
  auto L = [&]() {
    multi_gemm<<<dim3(jb.start[jb.n]), dim3(256), 0, stream>>>(jb, A, B, C, Km, ws);
    jb.n = 0;
    jb.start[0] = 0;
  };

  init_kernel<<<dim3(2048), dim3(256), 0, stream>>>(x0, xh, eh, ynh, uh0, dbnd,
                                                    arr, grp);
  m2_kernel<<<dim3(4096), dim3(256), 0, stream>>>(MT, sm, ws + oM2);
  wfir_kernel<<<dim3(8192), dim3(256), 0, stream>>>(ws + oM2, Phi, ws + oWfir);

  // ---- L1 ----
  J(4, 0, 3, 0, oKC, 128, 512, 256);
  J(1, 0, 1, 0, oA2, 512, 512, 512);
  J(1, 0, 2, 0, oApB, 512, 128, 512);
  J(3, 0, 1, 0, oCA, 256, 512, 512);
  L();
  // ---- L2 ----
  J(2, 0, 0, oKC, oBKC, 512, 512, 128);
  J(0, oA2, 0, oA2, oA4, 512, 512, 512);
  J(0, oCA, 1, 0, oCA + 131072, 256, 512, 512);
  J(1, 0, 0, oApB, oApB + 65536, 512, 128, 512);
  J(0, oWfir, 3, 0, oW0C, 128, 512, 256);
  L();
  axpy_acl<<<dim3(1024), dim3(256), 0, stream>>>(A, ws + oBKC, ws + oAcl, ws + oP);
  // ---- L3 ----
  J(0, oA4, 0, oA4, oA8, 512, 512, 512);
  J(0, oP, 0, oP, oP + 262144, 512, 512, 512);
  J(0, oCA, 0, oA2, oCA + 2 * 131072, 256, 512, 512);
  J(0, oCA + 131072, 0, oA2, oCA + 3 * 131072, 256, 512, 512);
  J(0, oW0C, 1, 0, oW0CA, 128, 512, 512);
  J(0, oW0C, 0, oA2, oW0CA + 65536, 128, 512, 512);
  J(0, oA2, 0, oApB, oApB + 2 * 65536, 512, 128, 512);
  J(0, oA2, 0, oApB + 65536, oApB + 3 * 65536, 512, 128, 512);
  L();
  // ---- L4 ----
  J(0, oA8, 0, oA8, oA16, 512, 512, 512);
  J(0, oP, 0, oP + 262144, oP + 2 * 262144, 512, 512, 512);
  J(0, oP + 262144, 0, oP + 262144, oP + 3 * 262144, 512, 512, 512);
  for (int i = 1; i <= 3; ++i)
    J(0, oCA + (i - 1) * 131072, 0, oA4, oCA + (i + 3) * 131072, 256, 512, 512);
  for (int i = 1; i <= 2; ++i)
    J(0, oW0CA + (i - 1) * 65536, 0, oA2, oW0CA + (i + 1) * 65536, 128, 512, 512);
  for (int k = 1; k <= 4; ++k)
    J(0, oA4, 0, oApB + (k - 1) * 65536, oApB + (k + 3) * 65536, 512, 128, 512);
  J(0, oP, 2, 0, oRn, 512, 128, 512);
  J(0, oP + 262144, 2, 0, oRn + 65536, 512, 128, 512);
  L();
  // ---- L5 ----
  J(0, oA16, 0, oA16, oA32, 512, 512, 512);
  for (int i = 1; i <= 4; ++i)
    J(0, oP + (i - 1) * 262144, 0, oP + 3 * 262144, oP + (i + 3) * 262144, 512, 512, 512);
  for (int i = 1; i <= 3; ++i)
    J(0, oW0CA + (i - 1) * 65536, 0, oA4, oW0CA + (i + 3) * 65536, 128, 512, 512);
  J(0, oP + 2 * 262144, 2, 0, oRn + 2 * 65536, 512, 128, 512);
  J(0, oP + 3 * 262144, 2, 0, oRn + 3 * 65536, 512, 128, 512);
  L();
  // ---- L6 ----
  for (int m = 0; m <= 7; ++m)
    J(0, oA32, 0, oApB + m * 65536, oAB33 + m * 65536, 512, 128, 512);
  for (int i = 5; i <= 7; ++i)
    J(0, oP + (i - 1) * 262144, 2, 0, oRn + (i - 1) * 65536, 512, 128, 512);
  L();
  // ---- L7 ----
  for (int m = 0; m <= 6; ++m)
    J(3, 0, 0, oAB33 + m * 65536, oCAB33 + m * 32768, 256, 128, 512);
  for (int m = 0; m <= 6; ++m)
    J(0, oW0C, 0, oAB33 + m * 65536, oW0CAB33 + m * 16384, 128, 128, 512);
  L();

  main_kernel<<<dim3(NWG), dim3(TPB), 0, stream>>>(
      B, C, x0, ws + oWfir, ws + oKC, ws + oW0C, ws + oP, ws + oCA,
      ws + oW0CA, ws + oRn, ws + oAB33, ws + oCAB33, ws + oW0CAB33,
      ws + oA8, xh, uh0, eh, ynh, dbnd, arr, grp);

  cost_kernel<<<dim3(1024), dim3(256), 0, stream>>>(C, Q, R, xh, uh0,
                                                    (float*)d_out);
}